// Round 3
// baseline (480.255 us; speedup 1.0000x reference)
//
#include <hip/hip_runtime.h>
#include <stdint.h>

#define QLEN 1024
#define KLEN 2048
#define BSZ  4
#define NH   16
#define HD   64
#define EMB  1024
#define PREVL 1024

typedef __attribute__((ext_vector_type(4))) float f32x4;
typedef __attribute__((ext_vector_type(8))) short bf16x8;

__device__ __forceinline__ unsigned short f2bf(float f){
  unsigned u = __float_as_uint(f);
  u += 0x7fffu + ((u >> 16) & 1u);
  return (unsigned short)(u >> 16);
}
__device__ __forceinline__ float bf2f(unsigned short s){
  return __uint_as_float(((unsigned)s) << 16);
}

__device__ __forceinline__ void gload_lds16(const void* g, void* l){
  __builtin_amdgcn_global_load_lds((const __attribute__((address_space(1))) void*)g,
                                   (__attribute__((address_space(3))) void*)l, 16, 0, 0);
}

// ---------------- fused 5x W transpose: f32 [k][n] -> bf16 [n][k] ----------------
__global__ void txl_transpose5(const float* __restrict__ w0, const float* __restrict__ w1,
                               const float* __restrict__ w2, const float* __restrict__ w3,
                               const float* __restrict__ w4,
                               unsigned short* __restrict__ o0, unsigned short* __restrict__ o1,
                               unsigned short* __restrict__ o2, unsigned short* __restrict__ o3,
                               unsigned short* __restrict__ o4){
  const float* in; unsigned short* out;
  switch (blockIdx.z){
    case 0: in = w0; out = o0; break;
    case 1: in = w1; out = o1; break;
    case 2: in = w2; out = o2; break;
    case 3: in = w3; out = o3; break;
    default: in = w4; out = o4; break;
  }
  __shared__ float tile[32][33];
  int tx = threadIdx.x, ty = threadIdx.y;
  int k0 = blockIdx.y * 32, n0 = blockIdx.x * 32;
  #pragma unroll
  for (int j = 0; j < 32; j += 8)
    tile[ty + j][tx] = in[(size_t)(k0 + ty + j) * EMB + n0 + tx];
  __syncthreads();
  #pragma unroll
  for (int j = 0; j < 32; j += 8)
    out[(size_t)(n0 + ty + j) * EMB + k0 + tx] = f2bf(tile[tx][ty + j]);
}

// ---------------- cg[h][r] = sum_d (U-V)[h,d] * R'[h,r,d] ----------------
__global__ void txl_cuv(const unsigned short* __restrict__ Rb, const float* __restrict__ U,
                        const float* __restrict__ V, float* __restrict__ cg){
  int idx = blockIdx.x * 256 + threadIdx.x;      // 16*2048
  int h = idx >> 11, r = idx & 2047;
  const bf16x8* rp = (const bf16x8*)(Rb + ((size_t)h * KLEN + r) * HD);
  float s = 0.f;
  #pragma unroll
  for (int c8 = 0; c8 < 8; ++c8){
    bf16x8 v8 = rp[c8];
    #pragma unroll
    for (int u = 0; u < 8; ++u){
      int d = c8 * 8 + u;
      s += (U[(h << 6) + d] - V[(h << 6) + d]) * bf2f((unsigned short)v8[u]);
    }
  }
  cg[idx] = s;
}

// ---------------- GEMM: C[M][1024] = A[M][1024] @ Wt^T (+bias) ----------------
// Wt is bf16 [n][k]. MODE: 0=Q (writes Qu only), 1=K, 2=V(transposed out), 3=R, 4=O(f32 out)
template<int MODE>
__global__ __launch_bounds__(256)
void txl_gemm(const void* __restrict__ Ag, const unsigned short* __restrict__ Wt,
              const float* __restrict__ bias, const float* __restrict__ Ub,
              void* __restrict__ out0){
  const int tid = threadIdx.x;
  const int lane = tid & 63, wave = tid >> 6;
  const int lr = lane & 15, lg = lane >> 4;
  const int wm = wave >> 1, wn = wave & 1;
  const int m0 = blockIdx.y * 128, n0 = blockIdx.x * 128;
  __shared__ unsigned short At[128 * 64];
  __shared__ unsigned short Bt[128 * 64];
  f32x4 acc[4][4] = {};

  for (int kt = 0; kt < EMB / 64; ++kt){
    const int k0 = kt * 64;
    __syncthreads();
    // ---- stage A tile [128][64] ----
    if constexpr (MODE == 4){
      const unsigned short* A = (const unsigned short*)Ag;
      #pragma unroll
      for (int j = 0; j < 4; ++j){
        int row = j * 32 + (tid >> 3);
        int g = (tid & 7) ^ (row & 7);
        gload_lds16(A + (size_t)(m0 + row) * EMB + k0 + g * 8, &At[j * 2048 + wave * 512]);
      }
    } else {
      const float* A = (const float*)Ag;
      int row = tid >> 1, half = tid & 1;
      const float* srow = A + (size_t)(m0 + row) * EMB + k0 + half * 32;
      #pragma unroll
      for (int c = 0; c < 4; ++c){
        bf16x8 pk;
        #pragma unroll
        for (int u = 0; u < 8; ++u) pk[u] = (short)f2bf(srow[c * 8 + u]);
        int g = half * 4 + c;
        int cl = g ^ (row & 7);
        *(bf16x8*)&At[row * 64 + cl * 8] = pk;
      }
    }
    // ---- stage B tile [128][64] from Wt rows n0..n0+127 ----
    #pragma unroll
    for (int j = 0; j < 4; ++j){
      int row = j * 32 + (tid >> 3);
      int g = (tid & 7) ^ (row & 7);
      gload_lds16(Wt + (size_t)(n0 + row) * EMB + k0 + g * 8, &Bt[j * 2048 + wave * 512]);
    }
    __syncthreads();
    #pragma unroll
    for (int ks = 0; ks < 2; ++ks){
      bf16x8 af[4], bfr[4];
      #pragma unroll
      for (int mb = 0; mb < 4; ++mb){
        int row = wm * 64 + mb * 16 + lr;
        af[mb] = *(const bf16x8*)&At[row * 64 + ((lg + 4 * ks) ^ (row & 7)) * 8];
      }
      #pragma unroll
      for (int nb = 0; nb < 4; ++nb){
        int row = wn * 64 + nb * 16 + lr;
        bfr[nb] = *(const bf16x8*)&Bt[row * 64 + ((lg + 4 * ks) ^ (row & 7)) * 8];
      }
      __builtin_amdgcn_s_setprio(1);
      #pragma unroll
      for (int mb = 0; mb < 4; ++mb)
        #pragma unroll
        for (int nb = 0; nb < 4; ++nb)
          acc[mb][nb] = __builtin_amdgcn_mfma_f32_16x16x32_bf16(af[mb], bfr[nb], acc[mb][nb], 0, 0, 0);
      __builtin_amdgcn_s_setprio(0);
    }
  }
  // ---- epilogue ----
  #pragma unroll
  for (int mb = 0; mb < 4; ++mb){
    #pragma unroll
    for (int nb = 0; nb < 4; ++nb){
      #pragma unroll
      for (int i = 0; i < 4; ++i){
        int m = m0 + wm * 64 + mb * 16 + 4 * lg + i;
        int n = n0 + wn * 64 + nb * 16 + lr;
        float v = acc[mb][nb][i];
        if constexpr (MODE == 0){
          int q = m >> 2, b = m & 3, h = n >> 6, d = n & 63;
          size_t idx = ((((size_t)b * NH + h) * QLEN) + q) * HD + d;
          ((unsigned short*)out0)[idx] = f2bf(v + bias[n] + Ub[(h << 6) + d]);
        } else if constexpr (MODE == 1){
          int kp = m >> 2, b = m & 3, h = n >> 6, d = n & 63;
          ((unsigned short*)out0)[((((size_t)b * NH + h) * KLEN) + kp) * HD + d] = f2bf(v + bias[n]);
        } else if constexpr (MODE == 2){
          int kp = m >> 2, b = m & 3, h = n >> 6, d = n & 63;
          ((unsigned short*)out0)[((((size_t)b * NH + h) * HD) + d) * KLEN + kp] = f2bf(v + bias[n]);
        } else if constexpr (MODE == 3){
          int h = n >> 6, d = n & 63;
          ((unsigned short*)out0)[((size_t)h * KLEN + m) * HD + d] = f2bf(v);
        } else {
          ((float*)out0)[(size_t)m * EMB + n] = v + bias[n];
        }
      }
    }
  }
}

// ---------------- fused attention ----------------
// 1-D grid of 1024 blocks (XCD-swizzled), 256 threads = 4 waves x 16 q-rows
__global__ __launch_bounds__(256)
void txl_attn(const unsigned short* __restrict__ Qu, const unsigned short* __restrict__ Kb,
              const unsigned short* __restrict__ Vt, const unsigned short* __restrict__ Rb,
              const float* __restrict__ cg, unsigned short* __restrict__ alpha){
  const int tid = threadIdx.x, lane = tid & 63, wave = tid >> 6;
  const int lr = lane & 15, lg = lane >> 4;
  // XCD swizzle: 8 consecutive (h,b) combos per XCD; longest blocks (high qt) first
  const int wg = (blockIdx.x & 7) * 128 + (blockIdx.x >> 3);
  const int hb = wg >> 4;
  const int qt = 15 - (wg & 15);
  const int h = hb & 15, b = hb >> 4;
  const int q0 = qt * 64;
  const int myq0 = q0 + 16 * wave;

  __shared__ union { unsigned short qu[64 * 64]; unsigned short p[4][16 * 64]; } sm_u;
  __shared__ unsigned short sm_k[64 * 64];
  __shared__ unsigned short sm_v[64 * 64];
  __shared__ unsigned short sm_r[128 * 64];
  __shared__ float sm_c[128];

  const unsigned short* quB = Qu + (((size_t)b * NH + h) * QLEN) * HD;
  const unsigned short* kB  = Kb + (((size_t)b * NH + h) * KLEN) * HD;
  const unsigned short* vB  = Vt + (((size_t)b * NH + h) * HD) * KLEN;
  const unsigned short* rB  = Rb + ((size_t)h * KLEN) * HD;
  const float* cB = cg + ((size_t)h << 11);

  // stage Q tile (async; drained at barrier), then hoist this wave's fragments
  #pragma unroll
  for (int j = 0; j < 2; ++j){
    int row = j * 32 + (tid >> 3);
    int g = (tid & 7) ^ (row & 7);
    gload_lds16(quB + (size_t)(q0 + row) * HD + g * 8, &sm_u.qu[j * 2048 + wave * 512]);
  }
  __syncthreads();
  bf16x8 qf[2];
  {
    int qrow = 16 * wave + lr;
    #pragma unroll
    for (int ks = 0; ks < 2; ++ks)
      qf[ks] = *(const bf16x8*)&sm_u.qu[qrow * 64 + ((lg + 4 * ks) ^ (qrow & 7)) * 8];
  }

  f32x4 o[4] = {};
  float mx[4], ls[4];
  #pragma unroll
  for (int i = 0; i < 4; ++i){ mx[i] = -3e38f; ls[i] = 0.f; }

  int nk = qt + 17; if (nk > KLEN / 64) nk = KLEN / 64;

  for (int kt = 0; kt < nk; ++kt){
    const int k0 = kt * 64;
    const int rbase = k0 + (QLEN - 64) - q0;   // shared R-band origin
    __syncthreads();
    // stage K, V tiles
    #pragma unroll
    for (int j = 0; j < 2; ++j){
      int row = j * 32 + (tid >> 3);
      int g = (tid & 7) ^ (row & 7);
      gload_lds16(kB + (size_t)(k0 + row) * HD + g * 8, &sm_k[j * 2048 + wave * 512]);
      gload_lds16(vB + (size_t)row * KLEN + k0 + g * 8, &sm_v[j * 2048 + wave * 512]);
    }
    // stage R band (128 rows, clamped)
    #pragma unroll
    for (int j = 0; j < 4; ++j){
      int row = j * 32 + (tid >> 3);
      int g = (tid & 7) ^ (row & 7);
      int r = rbase + row; if (r < 0) r = 0; if (r > KLEN - 1) r = KLEN - 1;
      gload_lds16(rB + (size_t)r * HD + g * 8, &sm_r[j * 2048 + wave * 512]);
    }
    // stage cg band
    if (tid < 128){
      int r = rbase + tid; if (r < 0) r = 0; if (r > KLEN - 1) r = KLEN - 1;
      sm_c[tid] = cB[r];
    }
    __syncthreads();

    // content scores S_c[16q][64k] and position band T[16q][80r], both with A = Qu frag
    f32x4 sc[4] = {};
    f32x4 tt[5] = {};
    const int roff = 48 - 16 * wave;
    __builtin_amdgcn_s_setprio(1);
    #pragma unroll
    for (int ks = 0; ks < 2; ++ks){
      #pragma unroll
      for (int nb = 0; nb < 4; ++nb){
        int row = nb * 16 + lr;
        bf16x8 bb = *(const bf16x8*)&sm_k[row * 64 + ((lg + 4 * ks) ^ (row & 7)) * 8];
        sc[nb] = __builtin_amdgcn_mfma_f32_16x16x32_bf16(qf[ks], bb, sc[nb], 0, 0, 0);
      }
      #pragma unroll
      for (int rb = 0; rb < 5; ++rb){
        int row = roff + rb * 16 + lr;
        bf16x8 bb = *(const bf16x8*)&sm_r[row * 64 + ((lg + 4 * ks) ^ (row & 7)) * 8];
        tt[rb] = __builtin_amdgcn_mfma_f32_16x16x32_bf16(qf[ks], bb, tt[rb], 0, 0, 0);
      }
    }
    __builtin_amdgcn_s_setprio(0);

    // diagonal select via in-group shuffle, mask, online softmax, write P
    #pragma unroll
    for (int i = 0; i < 4; ++i){
      int qq = 4 * lg + i;
      int qglob = myq0 + qq;
      int t = lr + 15 - qq;                    // 0..30
      int srcl = (lane & 48) | (t & 15);
      int hi = t >> 4;
      float w[5];
      #pragma unroll
      for (int j = 0; j < 5; ++j) w[j] = __shfl(tt[j][i], srcl, 64);
      float sv[4];
      float rowm = -3e38f;
      #pragma unroll
      for (int nb = 0; nb < 4; ++nb){
        int kk = nb * 16 + lr;
        float tv = (hi ? w[nb + 1] : w[nb]) - sm_c[roff + nb * 16 + t];
        float s = (sc[nb][i] + tv) * 0.03125f;
        if (k0 + kk > qglob + PREVL) s = -1e30f;
        sv[nb] = s;
        rowm = fmaxf(rowm, s);
      }
      #pragma unroll
      for (int off = 1; off < 16; off <<= 1)
        rowm = fmaxf(rowm, __shfl_xor(rowm, off));
      float mnew = fmaxf(mx[i], rowm);
      float scale = __expf(mx[i] - mnew);
      mx[i] = mnew;
      float rsum = 0.f;
      #pragma unroll
      for (int nb = 0; nb < 4; ++nb){
        float p = __expf(sv[nb] - mnew);
        rsum += p;
        int kk = nb * 16 + lr;
        sm_u.p[wave][qq * 64 + (((kk >> 3) ^ (qq & 7)) << 3) + (kk & 7)] = f2bf(p);
      }
      #pragma unroll
      for (int off = 1; off < 16; off <<= 1)
        rsum += __shfl_xor(rsum, off);
      ls[i] = ls[i] * scale + rsum;
      #pragma unroll
      for (int db = 0; db < 4; ++db) o[db][i] *= scale;
    }
    asm volatile("s_waitcnt lgkmcnt(0)" ::: "memory");

    // PV: O[16q][64d] += P @ V
    __builtin_amdgcn_s_setprio(1);
    #pragma unroll
    for (int ks = 0; ks < 2; ++ks){
      bf16x8 pa = *(const bf16x8*)&sm_u.p[wave][lr * 64 + ((lg + 4 * ks) ^ (lr & 7)) * 8];
      #pragma unroll
      for (int db = 0; db < 4; ++db){
        int row = db * 16 + lr;
        bf16x8 bb = *(const bf16x8*)&sm_v[row * 64 + ((lg + 4 * ks) ^ (row & 7)) * 8];
        o[db] = __builtin_amdgcn_mfma_f32_16x16x32_bf16(pa, bb, o[db], 0, 0, 0);
      }
    }
    __builtin_amdgcn_s_setprio(0);
  }

  // epilogue: alpha[q][b][h*64+d] bf16
  #pragma unroll
  for (int i = 0; i < 4; ++i){
    float inv = 1.0f / ls[i];
    int q = myq0 + 4 * lg + i;
    #pragma unroll
    for (int db = 0; db < 4; ++db){
      int e = (h << 6) + db * 16 + lr;
      alpha[((size_t)q * BSZ + b) * EMB + e] = f2bf(o[db][i] * inv);
    }
  }
}

extern "C" void kernel_launch(void* const* d_in, const int* in_sizes, int n_in,
                              void* d_out, int out_size, void* d_ws, size_t ws_size,
                              hipStream_t stream) {
  const float* query = (const float*)d_in[0];
  const float* key   = (const float*)d_in[1];
  const float* value = (const float*)d_in[2];
  const float* pos   = (const float*)d_in[3];
  const float* U     = (const float*)d_in[4];
  const float* V     = (const float*)d_in[5];
  const float* Wq    = (const float*)d_in[6];
  const float* bq    = (const float*)d_in[7];
  const float* Wk    = (const float*)d_in[8];
  const float* bk    = (const float*)d_in[9];
  const float* Wv    = (const float*)d_in[10];
  const float* bv    = (const float*)d_in[11];
  const float* Wp    = (const float*)d_in[12];
  const float* Wo    = (const float*)d_in[13];
  const float* bo    = (const float*)d_in[14];

  char* w = (char*)d_ws;
  const size_t MB = 1u << 20;
  unsigned short* WqT = (unsigned short*)(w + 0 * MB);
  unsigned short* WkT = (unsigned short*)(w + 2 * MB);
  unsigned short* WvT = (unsigned short*)(w + 4 * MB);
  unsigned short* WpT = (unsigned short*)(w + 6 * MB);
  unsigned short* WoT = (unsigned short*)(w + 8 * MB);
  unsigned short* Qu  = (unsigned short*)(w + 10 * MB);
  float*          cgp = (float*)(w + 18 * MB);
  unsigned short* Kb  = (unsigned short*)(w + 26 * MB);
  unsigned short* Vt  = (unsigned short*)(w + 42 * MB);
  unsigned short* Rb  = (unsigned short*)(w + 58 * MB);
  unsigned short* alpha = (unsigned short*)(w + 62 * MB);

  txl_transpose5<<<dim3(32, 32, 5), dim3(32, 8), 0, stream>>>(Wq, Wk, Wv, Wp, Wo,
                                                              WqT, WkT, WvT, WpT, WoT);

  txl_gemm<0><<<dim3(8, 32), 256, 0, stream>>>((const void*)query, WqT, bq, U, (void*)Qu);
  txl_gemm<1><<<dim3(8, 64), 256, 0, stream>>>((const void*)key,   WkT, bk, nullptr, (void*)Kb);
  txl_gemm<2><<<dim3(8, 64), 256, 0, stream>>>((const void*)value, WvT, bv, nullptr, (void*)Vt);
  txl_gemm<3><<<dim3(8, 16), 256, 0, stream>>>((const void*)pos,   WpT, nullptr, nullptr, (void*)Rb);

  txl_cuv<<<dim3(128), 256, 0, stream>>>(Rb, U, V, cgp);

  txl_attn<<<dim3(1024), 256, 0, stream>>>(Qu, Kb, Vt, Rb, cgp, alpha);

  txl_gemm<4><<<dim3(8, 32), 256, 0, stream>>>((const void*)alpha, WoT, bo, nullptr, d_out);
}

// Round 4
// 415.383 us; speedup vs baseline: 1.1562x; 1.1562x over previous
//
#include <hip/hip_runtime.h>
#include <stdint.h>

#define QLEN 1024
#define KLEN 2048
#define BSZ  4
#define NH   16
#define HD   64
#define EMB  1024
#define PREVL 1024
#define SLOG2E 0.045084220027780106f   // (1/32) * log2(e): fold softmax scale + exp2 conversion

typedef __attribute__((ext_vector_type(4))) float f32x4;
typedef __attribute__((ext_vector_type(8))) short bf16x8;

__device__ __forceinline__ unsigned short f2bf(float f){
  unsigned u = __float_as_uint(f);
  u += 0x7fffu + ((u >> 16) & 1u);
  return (unsigned short)(u >> 16);
}
__device__ __forceinline__ float bf2f(unsigned short s){
  return __uint_as_float(((unsigned)s) << 16);
}

__device__ __forceinline__ void gload_lds16(const void* g, void* l){
  __builtin_amdgcn_global_load_lds((const __attribute__((address_space(1))) void*)g,
                                   (__attribute__((address_space(3))) void*)l, 16, 0, 0);
}

// ---------------- fused 5x W transpose: f32 [k][n] -> bf16 [n][k] ----------------
__global__ void txl_transpose5(const float* __restrict__ w0, const float* __restrict__ w1,
                               const float* __restrict__ w2, const float* __restrict__ w3,
                               const float* __restrict__ w4,
                               unsigned short* __restrict__ o0, unsigned short* __restrict__ o1,
                               unsigned short* __restrict__ o2, unsigned short* __restrict__ o3,
                               unsigned short* __restrict__ o4){
  const float* in; unsigned short* out;
  switch (blockIdx.z){
    case 0: in = w0; out = o0; break;
    case 1: in = w1; out = o1; break;
    case 2: in = w2; out = o2; break;
    case 3: in = w3; out = o3; break;
    default: in = w4; out = o4; break;
  }
  __shared__ float tile[32][33];
  int tx = threadIdx.x, ty = threadIdx.y;
  int k0 = blockIdx.y * 32, n0 = blockIdx.x * 32;
  #pragma unroll
  for (int j = 0; j < 32; j += 8)
    tile[ty + j][tx] = in[(size_t)(k0 + ty + j) * EMB + n0 + tx];
  __syncthreads();
  #pragma unroll
  for (int j = 0; j < 32; j += 8)
    out[(size_t)(n0 + ty + j) * EMB + k0 + tx] = f2bf(tile[tx][ty + j]);
}

// ---------------- f32 -> bf16 bulk convert (query|key|value|pos) ----------------
__global__ void txl_cvt(const float* __restrict__ q, const float* __restrict__ k,
                        const float* __restrict__ v, const float* __restrict__ p,
                        unsigned short* __restrict__ qo, unsigned short* __restrict__ ko,
                        unsigned short* __restrict__ vo, unsigned short* __restrict__ po){
  for (size_t c = (size_t)blockIdx.x * 256 + threadIdx.x; c < 2883584; c += (size_t)2048 * 256){
    const float* src; unsigned short* dst; size_t off;
    if (c < 524288)      { src = q; dst = qo; off = c; }
    else if (c < 1572864){ src = k; dst = ko; off = c - 524288; }
    else if (c < 2621440){ src = v; dst = vo; off = c - 1572864; }
    else                 { src = p; dst = po; off = c - 2621440; }
    f32x4 a = *(const f32x4*)(src + off * 8);
    f32x4 b = *(const f32x4*)(src + off * 8 + 4);
    bf16x8 r;
    #pragma unroll
    for (int u = 0; u < 4; ++u){ r[u] = (short)f2bf(a[u]); r[u + 4] = (short)f2bf(b[u]); }
    *(bf16x8*)(dst + off * 8) = r;
  }
}

// ---------------- cg[h][r] = SLOG2E * sum_d (U-V)[h,d] * R'[h,r,d] ----------------
__global__ void txl_cuv(const unsigned short* __restrict__ Rb, const float* __restrict__ U,
                        const float* __restrict__ V, float* __restrict__ cg){
  int idx = blockIdx.x * 256 + threadIdx.x;      // 16*2048
  int h = idx >> 11, r = idx & 2047;
  const bf16x8* rp = (const bf16x8*)(Rb + ((size_t)h * KLEN + r) * HD);
  float s = 0.f;
  #pragma unroll
  for (int c8 = 0; c8 < 8; ++c8){
    bf16x8 v8 = rp[c8];
    #pragma unroll
    for (int u = 0; u < 8; ++u){
      int d = c8 * 8 + u;
      s += (U[(h << 6) + d] - V[(h << 6) + d]) * bf2f((unsigned short)v8[u]);
    }
  }
  cg[idx] = s * SLOG2E;
}

// ---------------- GEMM: C[M][1024] = A[M][1024] @ Wt^T (+bias) ----------------
// A is bf16 [M][1024]; Wt is bf16 [n][k].
// MODE: 0=Q (scaled by SLOG2E, +U), 1=K, 2=V(transposed out), 3=R, 4=O(f32 out)
template<int MODE>
__global__ __launch_bounds__(256)
void txl_gemm(const unsigned short* __restrict__ Ag, const unsigned short* __restrict__ Wt,
              const float* __restrict__ bias, const float* __restrict__ Ub,
              void* __restrict__ out0){
  const int tid = threadIdx.x;
  const int lane = tid & 63, wave = tid >> 6;
  const int lr = lane & 15, lg = lane >> 4;
  const int wm = wave >> 1, wn = wave & 1;
  const int m0 = blockIdx.y * 128, n0 = blockIdx.x * 128;
  __shared__ unsigned short At[128 * 64];
  __shared__ unsigned short Bt[128 * 64];
  f32x4 acc[4][4] = {};

  for (int kt = 0; kt < EMB / 64; ++kt){
    const int k0 = kt * 64;
    __syncthreads();
    #pragma unroll
    for (int j = 0; j < 4; ++j){
      int row = j * 32 + (tid >> 3);
      int g = (tid & 7) ^ (row & 7);
      gload_lds16(Ag + (size_t)(m0 + row) * EMB + k0 + g * 8, &At[j * 2048 + wave * 512]);
      gload_lds16(Wt + (size_t)(n0 + row) * EMB + k0 + g * 8, &Bt[j * 2048 + wave * 512]);
    }
    __syncthreads();
    #pragma unroll
    for (int ks = 0; ks < 2; ++ks){
      bf16x8 af[4], bfr[4];
      #pragma unroll
      for (int mb = 0; mb < 4; ++mb){
        int row = wm * 64 + mb * 16 + lr;
        af[mb] = *(const bf16x8*)&At[row * 64 + ((lg + 4 * ks) ^ (row & 7)) * 8];
      }
      #pragma unroll
      for (int nb = 0; nb < 4; ++nb){
        int row = wn * 64 + nb * 16 + lr;
        bfr[nb] = *(const bf16x8*)&Bt[row * 64 + ((lg + 4 * ks) ^ (row & 7)) * 8];
      }
      __builtin_amdgcn_s_setprio(1);
      #pragma unroll
      for (int mb = 0; mb < 4; ++mb)
        #pragma unroll
        for (int nb = 0; nb < 4; ++nb)
          acc[mb][nb] = __builtin_amdgcn_mfma_f32_16x16x32_bf16(af[mb], bfr[nb], acc[mb][nb], 0, 0, 0);
      __builtin_amdgcn_s_setprio(0);
    }
  }
  #pragma unroll
  for (int mb = 0; mb < 4; ++mb){
    #pragma unroll
    for (int nb = 0; nb < 4; ++nb){
      #pragma unroll
      for (int i = 0; i < 4; ++i){
        int m = m0 + wm * 64 + mb * 16 + 4 * lg + i;
        int n = n0 + wn * 64 + nb * 16 + lr;
        float v = acc[mb][nb][i];
        if constexpr (MODE == 0){
          int q = m >> 2, b = m & 3, h = n >> 6, d = n & 63;
          size_t idx = ((((size_t)b * NH + h) * QLEN) + q) * HD + d;
          ((unsigned short*)out0)[idx] = f2bf((v + bias[n] + Ub[n]) * SLOG2E);
        } else if constexpr (MODE == 1){
          int kp = m >> 2, b = m & 3, h = n >> 6, d = n & 63;
          ((unsigned short*)out0)[((((size_t)b * NH + h) * KLEN) + kp) * HD + d] = f2bf(v + bias[n]);
        } else if constexpr (MODE == 2){
          int kp = m >> 2, b = m & 3, h = n >> 6, d = n & 63;
          ((unsigned short*)out0)[((((size_t)b * NH + h) * HD) + d) * KLEN + kp] = f2bf(v + bias[n]);
        } else if constexpr (MODE == 3){
          int h = n >> 6, d = n & 63;
          ((unsigned short*)out0)[((size_t)h * KLEN + m) * HD + d] = f2bf(v);
        } else {
          ((float*)out0)[(size_t)m * EMB + n] = v + bias[n];
        }
      }
    }
  }
}

// ---------------- fused attention ----------------
// 512 blocks (XCD-swizzled, work-paired qt order), 256 threads = 4 waves x 32 q-rows
__global__ __launch_bounds__(256)
void txl_attn(const unsigned short* __restrict__ Qu, const unsigned short* __restrict__ Kb,
              const unsigned short* __restrict__ Vt, const unsigned short* __restrict__ Rb,
              const float* __restrict__ cg, unsigned short* __restrict__ alpha){
  const int tid = threadIdx.x, lane = tid & 63, wave = tid >> 6;
  const int lr = lane & 15, lg = lane >> 4;
  const int wg = (blockIdx.x & 7) * 64 + (blockIdx.x >> 3);
  const int hb = wg >> 3;
  const int x7 = wg & 7;                       // qt order 7,0,6,1,5,2,4,3 -> co-resident pairs balance
  const int qt = (x7 & 1) ? (x7 >> 1) : (7 - (x7 >> 1));
  const int h = hb & 15, b = hb >> 4;
  const int q0 = qt * 128;

  __shared__ union { unsigned short q[128 * 64]; unsigned short p[4][32 * 64]; } sm_u;
  __shared__ unsigned short sm_k[64 * 64];
  __shared__ unsigned short sm_v[64 * 64];
  __shared__ unsigned short sm_r[192 * 64];
  __shared__ float sm_c[192];

  const unsigned short* quB = Qu + (((size_t)b * NH + h) * QLEN) * HD;
  const unsigned short* kB  = Kb + (((size_t)b * NH + h) * KLEN) * HD;
  const unsigned short* vB  = Vt + (((size_t)b * NH + h) * HD) * KLEN;
  const unsigned short* rB  = Rb + ((size_t)h * KLEN) * HD;
  const float* cB = cg + ((size_t)h << 11);

  // stage Q tile (128 rows), then hoist this wave's fragments
  #pragma unroll
  for (int j = 0; j < 4; ++j){
    int row = j * 32 + (tid >> 3);
    int g = (tid & 7) ^ (row & 7);
    gload_lds16(quB + (size_t)(q0 + row) * HD + g * 8, &sm_u.q[j * 2048 + wave * 512]);
  }
  __syncthreads();
  bf16x8 qf[2][2];
  #pragma unroll
  for (int j = 0; j < 2; ++j){
    int row = 32 * wave + 16 * j + lr;
    #pragma unroll
    for (int ks = 0; ks < 2; ++ks)
      qf[j][ks] = *(const bf16x8*)&sm_u.q[row * 64 + ((lg + 4 * ks) ^ (row & 7)) * 8];
  }

  f32x4 o[2][4] = {};
  float ls[2][4] = {{0.f,0.f,0.f,0.f},{0.f,0.f,0.f,0.f}};

  const int nk = (2 * qt + 18 < 32) ? (2 * qt + 18) : 32;
  const int bb0 = 6 - 2 * wave;                // this wave's global band-block base

  for (int kt = 0; kt < nk; ++kt){
    const int k0 = kt * 64;
    const int rb0 = k0 + 896 - q0;             // band origin (always >= 0)
    __syncthreads();
    // stage K, V tiles (64 rows each)
    #pragma unroll
    for (int j = 0; j < 2; ++j){
      int row = j * 32 + (tid >> 3);
      int g = (tid & 7) ^ (row & 7);
      gload_lds16(kB + (size_t)(k0 + row) * HD + g * 8, &sm_k[j * 2048 + wave * 512]);
      gload_lds16(vB + (size_t)row * KLEN + k0 + g * 8, &sm_v[j * 2048 + wave * 512]);
    }
    // stage R band (192 rows, clamped high; clamped rows only feed masked elements)
    #pragma unroll
    for (int j = 0; j < 6; ++j){
      int row = j * 32 + (tid >> 3);
      int g = (tid & 7) ^ (row & 7);
      int r = rb0 + row; if (r > KLEN - 1) r = KLEN - 1;
      gload_lds16(rB + (size_t)r * HD + g * 8, &sm_r[j * 2048 + wave * 512]);
    }
    if (tid < 192){
      int r = rb0 + tid; if (r > KLEN - 1) r = KLEN - 1;
      sm_c[tid] = cB[r];
    }
    __syncthreads();

    // content scores (2 q-subtiles x 64k) + position band (2 x 80r, sharing 12 B-reads)
    f32x4 sc[2][4] = {};
    f32x4 tq[2][5] = {};
    __builtin_amdgcn_s_setprio(1);
    #pragma unroll
    for (int ks = 0; ks < 2; ++ks){
      #pragma unroll
      for (int nb = 0; nb < 4; ++nb){
        int row = nb * 16 + lr;
        bf16x8 bb = *(const bf16x8*)&sm_k[row * 64 + ((lg + 4 * ks) ^ (row & 7)) * 8];
        sc[0][nb] = __builtin_amdgcn_mfma_f32_16x16x32_bf16(qf[0][ks], bb, sc[0][nb], 0, 0, 0);
        sc[1][nb] = __builtin_amdgcn_mfma_f32_16x16x32_bf16(qf[1][ks], bb, sc[1][nb], 0, 0, 0);
      }
      #pragma unroll
      for (int x6 = 0; x6 < 6; ++x6){
        int row = (bb0 + x6) * 16 + lr;
        bf16x8 br = *(const bf16x8*)&sm_r[row * 64 + ((lg + 4 * ks) ^ (row & 7)) * 8];
        if (x6 < 5) tq[1][x6]     = __builtin_amdgcn_mfma_f32_16x16x32_bf16(qf[1][ks], br, tq[1][x6], 0, 0, 0);
        if (x6 > 0) tq[0][x6 - 1] = __builtin_amdgcn_mfma_f32_16x16x32_bf16(qf[0][ks], br, tq[0][x6 - 1], 0, 0, 0);
      }
    }
    __builtin_amdgcn_s_setprio(0);

    // cg pre-subtract (per band column, before the diagonal shuffle)
    float cgl[6];
    #pragma unroll
    for (int x6 = 0; x6 < 6; ++x6) cgl[x6] = sm_c[(bb0 + x6) * 16 + lr];
    #pragma unroll
    for (int x = 0; x < 5; ++x){
      #pragma unroll
      for (int e = 0; e < 4; ++e){ tq[0][x][e] -= cgl[x + 1]; tq[1][x][e] -= cgl[x]; }
    }

    // diagonal select + mask + exp2 (fixed-max), deferred row-sum, write P
    #pragma unroll
    for (int j = 0; j < 2; ++j){
      const int qbase = q0 + 32 * wave + 16 * j;
      const bool mk = (k0 + 63 > qbase + PREVL);
      #pragma unroll
      for (int i = 0; i < 4; ++i){
        int qq = 4 * lg + i;
        int t = lr + 15 - qq;
        int srcl = (lane & 48) | (t & 15);
        int hi = t >> 4;
        float wv[5];
        #pragma unroll
        for (int x = 0; x < 5; ++x) wv[x] = __shfl(tq[j][x][i], srcl, 64);
        float rs = 0.f;
        #pragma unroll
        for (int nb = 0; nb < 4; ++nb){
          float s = sc[j][nb][i] + (hi ? wv[nb + 1] : wv[nb]);
          if (mk && (k0 + nb * 16 + lr > qbase + qq + PREVL)) s = -1e30f;
          float p = exp2f(s);
          rs += p;
          int kk = nb * 16 + lr, prow = 16 * j + qq;
          sm_u.p[wave][prow * 64 + (((kk >> 3) ^ (prow & 7)) << 3) + (kk & 7)] = f2bf(p);
        }
        ls[j][i] += rs;
      }
    }
    asm volatile("s_waitcnt lgkmcnt(0)" ::: "memory");

    // PV: O[32q][64d] += P @ V
    __builtin_amdgcn_s_setprio(1);
    #pragma unroll
    for (int ks = 0; ks < 2; ++ks){
      bf16x8 pa[2];
      #pragma unroll
      for (int j = 0; j < 2; ++j){
        int row = 16 * j + lr;
        pa[j] = *(const bf16x8*)&sm_u.p[wave][row * 64 + ((lg + 4 * ks) ^ (row & 7)) * 8];
      }
      #pragma unroll
      for (int db = 0; db < 4; ++db){
        int row = db * 16 + lr;
        bf16x8 bv = *(const bf16x8*)&sm_v[row * 64 + ((lg + 4 * ks) ^ (row & 7)) * 8];
        o[0][db] = __builtin_amdgcn_mfma_f32_16x16x32_bf16(pa[0], bv, o[0][db], 0, 0, 0);
        o[1][db] = __builtin_amdgcn_mfma_f32_16x16x32_bf16(pa[1], bv, o[1][db], 0, 0, 0);
      }
    }
    __builtin_amdgcn_s_setprio(0);
  }

  // final row-sum reduce + normalized output
  #pragma unroll
  for (int j = 0; j < 2; ++j){
    #pragma unroll
    for (int i = 0; i < 4; ++i){
      float s = ls[j][i];
      s += __shfl_xor(s, 1); s += __shfl_xor(s, 2);
      s += __shfl_xor(s, 4); s += __shfl_xor(s, 8);
      float inv = 1.0f / s;
      int q = q0 + 32 * wave + 16 * j + 4 * lg + i;
      #pragma unroll
      for (int db = 0; db < 4; ++db){
        int e = (h << 6) + db * 16 + lr;
        alpha[((size_t)q * BSZ + b) * EMB + e] = f2bf(o[j][db][i] * inv);
      }
    }
  }
}

extern "C" void kernel_launch(void* const* d_in, const int* in_sizes, int n_in,
                              void* d_out, int out_size, void* d_ws, size_t ws_size,
                              hipStream_t stream) {
  const float* query = (const float*)d_in[0];
  const float* key   = (const float*)d_in[1];
  const float* value = (const float*)d_in[2];
  const float* pos   = (const float*)d_in[3];
  const float* U     = (const float*)d_in[4];
  const float* V     = (const float*)d_in[5];
  const float* Wq    = (const float*)d_in[6];
  const float* bq    = (const float*)d_in[7];
  const float* Wk    = (const float*)d_in[8];
  const float* bk    = (const float*)d_in[9];
  const float* Wv    = (const float*)d_in[10];
  const float* bv    = (const float*)d_in[11];
  const float* Wp    = (const float*)d_in[12];
  const float* Wo    = (const float*)d_in[13];
  const float* bo    = (const float*)d_in[14];

  char* w = (char*)d_ws;
  const size_t MB = 1u << 20;
  unsigned short* WqT = (unsigned short*)(w + 0 * MB);
  unsigned short* WkT = (unsigned short*)(w + 2 * MB);
  unsigned short* WvT = (unsigned short*)(w + 4 * MB);
  unsigned short* WpT = (unsigned short*)(w + 6 * MB);
  unsigned short* WoT = (unsigned short*)(w + 8 * MB);
  unsigned short* Qu  = (unsigned short*)(w + 10 * MB);
  unsigned short* Kb  = (unsigned short*)(w + 18 * MB);
  unsigned short* Vt  = (unsigned short*)(w + 34 * MB);
  unsigned short* Rb  = (unsigned short*)(w + 50 * MB);
  float*          cgp = (float*)(w + 54 * MB);
  unsigned short* qbf = (unsigned short*)(w + 55 * MB);   // alpha overlays after GEMM0 is done
  unsigned short* kbf = (unsigned short*)(w + 63 * MB);
  unsigned short* vbf = (unsigned short*)(w + 79 * MB);
  unsigned short* pbf = (unsigned short*)(w + 95 * MB);
  unsigned short* alpha = qbf;

  txl_transpose5<<<dim3(32, 32, 5), dim3(32, 8), 0, stream>>>(Wq, Wk, Wv, Wp, Wo,
                                                              WqT, WkT, WvT, WpT, WoT);
  txl_cvt<<<dim3(2048), 256, 0, stream>>>(query, key, value, pos, qbf, kbf, vbf, pbf);

  txl_gemm<0><<<dim3(8, 32), 256, 0, stream>>>(qbf, WqT, bq, U, (void*)Qu);
  txl_gemm<1><<<dim3(8, 64), 256, 0, stream>>>(kbf, WkT, bk, nullptr, (void*)Kb);
  txl_gemm<2><<<dim3(8, 64), 256, 0, stream>>>(vbf, WvT, bv, nullptr, (void*)Vt);
  txl_gemm<3><<<dim3(8, 16), 256, 0, stream>>>(pbf, WpT, nullptr, nullptr, (void*)Rb);

  txl_cuv<<<dim3(128), 256, 0, stream>>>(Rb, U, V, cgp);

  txl_attn<<<dim3(512), 256, 0, stream>>>(Qu, Kb, Vt, Rb, cgp, alpha);

  txl_gemm<4><<<dim3(8, 32), 256, 0, stream>>>(alpha, WoT, bo, nullptr, d_out);
}